// Round 16
// baseline (339.652 us; speedup 1.0000x reference)
//
#include <hip/hip_runtime.h>
#include <math.h>

#define HEADS 2
#define CH    128          // per-head channels
#define HC    256          // HEADS*CH
#define NEG   0.2f         // leaky_relu slope

typedef __attribute__((ext_vector_type(8))) short  bfrag8;   // 8 bf16 (4 VGPR)
typedef __attribute__((ext_vector_type(4))) float  f32x4;    // MFMA accumulator

// round-to-nearest-even fp32 -> bf16 (as raw u16)
__device__ inline unsigned short f2bf_rne(float x) {
    unsigned u = __float_as_uint(x);
    u += 0x7fffu + ((u >> 16) & 1u);
    return (unsigned short)(u >> 16);
}

// ---------------------------------------------------------------------------
// fused W cast+transpose for both layers: W[K][HC] fp32 -> Wt[HC][K] bf16
// ---------------------------------------------------------------------------
__global__ __launch_bounds__(256)
void prep_w_kernel(const float* __restrict__ W1, const float* __restrict__ W2,
                   unsigned short* __restrict__ wt1, unsigned short* __restrict__ wt2,
                   int K1) {
    int idx = blockIdx.x * 256 + threadIdx.x;
    const int n1 = K1 * HC;
    if (idx < n1) {
        const int k = idx >> 8, n = idx & 255;
        wt1[(size_t)n * K1 + k] = f2bf_rne(W1[idx]);
    } else {
        idx -= n1;
        if (idx < HC * HC) {
            const int k = idx >> 8, n = idx & 255;
            wt2[(size_t)n * HC + k] = f2bf_rne(W2[idx]);
        }
    }
}

// ---------------------------------------------------------------------------
// fused va for both layers: va[k][4] = {src_h0, src_h1, dst_h0, dst_h1}
// one wave per k row.
// ---------------------------------------------------------------------------
__device__ inline void va_row(const float* __restrict__ W, const float* __restrict__ a_src,
                              const float* __restrict__ a_dst, float* __restrict__ va,
                              int k, int lane) {
    const int c0 = lane * 4;
    const float4 w4 = *reinterpret_cast<const float4*>(&W[(size_t)k * HC + c0]);
    const float4 s4 = *reinterpret_cast<const float4*>(&a_src[c0]);
    const float4 d4 = *reinterpret_cast<const float4*>(&a_dst[c0]);
    float ps = w4.x * s4.x + w4.y * s4.y + w4.z * s4.z + w4.w * s4.w;
    float pd = w4.x * d4.x + w4.y * d4.y + w4.z * d4.z + w4.w * d4.w;
    #pragma unroll
    for (int m = 1; m <= 16; m <<= 1) {
        ps += __shfl_xor(ps, m);
        pd += __shfl_xor(pd, m);
    }
    if (lane == 0)  { va[k * 4 + 0] = ps; va[k * 4 + 2] = pd; }
    if (lane == 32) { va[k * 4 + 1] = ps; va[k * 4 + 3] = pd; }
}

__global__ __launch_bounds__(256)
void prep_va_kernel(const float* __restrict__ W1, const float* __restrict__ as1,
                    const float* __restrict__ ad1, float* __restrict__ va1,
                    const float* __restrict__ W2, const float* __restrict__ as2,
                    const float* __restrict__ ad2, float* __restrict__ va2, int K1) {
    int g = (blockIdx.x * 256 + threadIdx.x) >> 6;
    const int lane = threadIdx.x & 63;
    if (g < K1)           va_row(W1, as1, ad1, va1, g, lane);
    else { g -= K1; if (g < HC) va_row(W2, as2, ad2, va2, g, lane); }
}

// ---------------------------------------------------------------------------
// fused xprep (per node: bf16 cast + exact fp32 logits) AND hist (per edge).
// blocks [0, nxp) do xprep; blocks [nxp, nxp+nhb) do hist.
// ---------------------------------------------------------------------------
__global__ __launch_bounds__(256)
void xprep_hist_kernel(const float* __restrict__ x, const float* __restrict__ va,
                       unsigned short* __restrict__ xb, float* __restrict__ as_out,
                       float* __restrict__ ad_out, int N, int K,
                       const int* __restrict__ dst, int* __restrict__ counts,
                       int E, int nxp) {
    if ((int)blockIdx.x >= nxp) {
        const int e = ((int)blockIdx.x - nxp) * 256 + threadIdx.x;
        if (e < E) atomicAdd(&counts[dst[e]], 1);
        return;
    }
    const int i    = (blockIdx.x * 256 + threadIdx.x) >> 6;
    const int lane = threadIdx.x & 63;
    if (i >= N) return;
    const float2 v = reinterpret_cast<const float2*>(&x[(size_t)i * K])[lane];
    ushort2 bv; bv.x = f2bf_rne(v.x); bv.y = f2bf_rne(v.y);
    reinterpret_cast<ushort2*>(&xb[(size_t)i * K])[lane] = bv;

    const float4 a0 = reinterpret_cast<const float4*>(va)[lane * 2 + 0];
    const float4 a1 = reinterpret_cast<const float4*>(va)[lane * 2 + 1];
    float p0 = v.x * a0.x + v.y * a1.x;
    float p1 = v.x * a0.y + v.y * a1.y;
    float p2 = v.x * a0.z + v.y * a1.z;
    float p3 = v.x * a0.w + v.y * a1.w;
    #pragma unroll
    for (int m = 1; m <= 32; m <<= 1) {
        p0 += __shfl_xor(p0, m);
        p1 += __shfl_xor(p1, m);
        p2 += __shfl_xor(p2, m);
        p3 += __shfl_xor(p3, m);
    }
    if (lane == 0) {
        as_out[i * 2 + 0] = p0; as_out[i * 2 + 1] = p1;
        ad_out[i * 2 + 0] = p2; ad_out[i * 2 + 1] = p3;
    }
}

// ---------------------------------------------------------------------------
// hlogit: layer-2 logits from bf16 h rows. one wave per node; lane covers
// 4 channels (8 B load); logit error from bf16 h ~2e-3 (negligible).
// ---------------------------------------------------------------------------
__global__ __launch_bounds__(256)
void hlogit_kernel(const unsigned short* __restrict__ hb, const float* __restrict__ va,
                   float* __restrict__ as2, float* __restrict__ ad2, int N) {
    const int i    = (blockIdx.x * 256 + threadIdx.x) >> 6;
    const int lane = threadIdx.x & 63;
    if (i >= N) return;
    const uint2 q = reinterpret_cast<const uint2*>(&hb[(size_t)i * HC])[lane];
    float f[4];
    f[0] = __uint_as_float(q.x << 16);
    f[1] = __uint_as_float(q.x & 0xffff0000u);
    f[2] = __uint_as_float(q.y << 16);
    f[3] = __uint_as_float(q.y & 0xffff0000u);
    float p0 = 0.f, p1 = 0.f, p2 = 0.f, p3 = 0.f;
    #pragma unroll
    for (int r = 0; r < 4; ++r) {
        const float4 vv = reinterpret_cast<const float4*>(va)[lane * 4 + r];
        p0 = fmaf(f[r], vv.x, p0);
        p1 = fmaf(f[r], vv.y, p1);
        p2 = fmaf(f[r], vv.z, p2);
        p3 = fmaf(f[r], vv.w, p3);
    }
    #pragma unroll
    for (int m = 1; m <= 32; m <<= 1) {
        p0 += __shfl_xor(p0, m);
        p1 += __shfl_xor(p1, m);
        p2 += __shfl_xor(p2, m);
        p3 += __shfl_xor(p3, m);
    }
    if (lane == 0) {
        as2[i * 2 + 0] = p0; as2[i * 2 + 1] = p1;
        ad2[i * 2 + 0] = p2; ad2[i * 2 + 1] = p3;
    }
}

// ---------------------------------------------------------------------------
// Single-pass bf16 message GEMM: xWb[M,HC] = bf16( Ab[M,K] @ Wt^T )
// tile 128x128, BK=64, 4 waves (2x2), 32 MFMA/k-step.
// ---------------------------------------------------------------------------
__global__ __launch_bounds__(256)
void gemm_msg_kernel(const unsigned short* __restrict__ Ab,
                     const unsigned short* __restrict__ Wt,
                     unsigned short* __restrict__ xWb, int M, int K) {
    __shared__ unsigned short Ah[128][72];   // 64 k + 8 pad (144 B stride)
    __shared__ unsigned short Bh[128][72];

    const int t    = threadIdx.x;
    const int row0 = blockIdx.x * 128;
    const int col0 = blockIdx.y * 128;
    const int lane = t & 63;
    const int wid  = t >> 6;
    const int wr   = wid >> 1;
    const int wc   = wid & 1;

    f32x4 acc[4][4] = {};

    const int arow = t & 127;        // staging row / col
    const int aseg = (t >> 7) * 32;  // k segment 0 or 32

    for (int kk = 0; kk < K; kk += 64) {
        {
            const int gr = row0 + arow;
            #pragma unroll
            for (int q = 0; q < 4; ++q) {
                bfrag8 v = {0,0,0,0,0,0,0,0};
                if (gr < M)
                    v = *reinterpret_cast<const bfrag8*>(&Ab[(size_t)gr * K + kk + aseg + q * 8]);
                *reinterpret_cast<bfrag8*>(&Ah[arow][aseg + q * 8]) = v;
            }
            #pragma unroll
            for (int q = 0; q < 4; ++q) {
                const bfrag8 w = *reinterpret_cast<const bfrag8*>(
                    &Wt[(size_t)(col0 + arow) * K + kk + aseg + q * 8]);
                *reinterpret_cast<bfrag8*>(&Bh[arow][aseg + q * 8]) = w;
            }
        }
        __syncthreads();

        const int ko = (lane >> 4) * 8;
        #pragma unroll
        for (int kb = 0; kb < 64; kb += 32) {
            bfrag8 ah[4], bh[4];
            #pragma unroll
            for (int m = 0; m < 4; ++m)
                ah[m] = *reinterpret_cast<const bfrag8*>(&Ah[wr * 64 + m * 16 + (lane & 15)][kb + ko]);
            #pragma unroll
            for (int n = 0; n < 4; ++n)
                bh[n] = *reinterpret_cast<const bfrag8*>(&Bh[wc * 64 + n * 16 + (lane & 15)][kb + ko]);
            #pragma unroll
            for (int m = 0; m < 4; ++m)
                #pragma unroll
                for (int n = 0; n < 4; ++n)
                    acc[m][n] = __builtin_amdgcn_mfma_f32_16x16x32_bf16(ah[m], bh[n], acc[m][n], 0, 0, 0);
        }
        __syncthreads();
    }

    // epilogue: bf16 stores (C/D layout col=lane&15, row=(lane>>4)*4+reg)
    #pragma unroll
    for (int m = 0; m < 4; ++m) {
        #pragma unroll
        for (int reg = 0; reg < 4; ++reg) {
            const int gr = row0 + wr * 64 + m * 16 + (lane >> 4) * 4 + reg;
            if (gr < M) {
                unsigned short* rp = &xWb[(size_t)gr * HC + col0];
                #pragma unroll
                for (int n = 0; n < 4; ++n)
                    rp[wc * 64 + n * 16 + (lane & 15)] = f2bf_rne(acc[m][n][reg]);
            }
        }
    }
}

// ---------------------------------------------------------------------------
// CSR scans + scatter
// ---------------------------------------------------------------------------
__global__ __launch_bounds__(256)
void scan_local_kernel(int* __restrict__ data, int* __restrict__ chunk_sum, int N) {
    __shared__ int s[256];
    const int t   = threadIdx.x;
    const int idx = blockIdx.x * 256 + t;
    const int v   = (idx < N) ? data[idx] : 0;
    s[t] = v;
    __syncthreads();
    #pragma unroll
    for (int off = 1; off < 256; off <<= 1) {
        int x = (t >= off) ? s[t - off] : 0;
        __syncthreads();
        s[t] += x;
        __syncthreads();
    }
    if (idx < N) data[idx] = s[t] - v;        // exclusive
    if (t == 255) chunk_sum[blockIdx.x] = s[255];
}

__global__ __launch_bounds__(256)
void scan_chunks_kernel(int* __restrict__ chunk, int nb) {
    __shared__ int s[256];
    const int t = threadIdx.x;
    const int v = (t < nb) ? chunk[t] : 0;
    s[t] = v;
    __syncthreads();
    #pragma unroll
    for (int off = 1; off < 256; off <<= 1) {
        int x = (t >= off) ? s[t - off] : 0;
        __syncthreads();
        s[t] += x;
        __syncthreads();
    }
    if (t < nb) chunk[t] = s[t] - v;
}

__global__ __launch_bounds__(256)
void add_offsets_kernel(const int* __restrict__ excl, const int* __restrict__ chunk_excl,
                        int* __restrict__ row_ptr, int* __restrict__ cursor,
                        int N, int E) {
    const int idx = blockIdx.x * 256 + threadIdx.x;
    if (idx < N) {
        const int rp = excl[idx] + chunk_excl[idx >> 8];
        row_ptr[idx] = rp;
        cursor[idx]  = rp;
    }
    if (idx == 0) row_ptr[N] = E;
}

__global__ __launch_bounds__(256)
void scatter_kernel(const int* __restrict__ src, const int* __restrict__ dst,
                    int* __restrict__ cursor, int* __restrict__ col_idx, int E) {
    const int e = blockIdx.x * 256 + threadIdx.x;
    if (e < E) {
        const int pos = atomicAdd(&cursor[dst[e]], 1);
        col_idx[pos] = src[e];
    }
}

// ---------------------------------------------------------------------------
// gather aggregation: one wave per target node — EXACT r8-optimal loop shape
// (bf16 messages, uint4+shift unpack, expf, 2 edge streams, idx-only
// prefetch; VGPR-lean). mode 1: ELU -> bf16 h row. mode 0: fp32 output.
// Layer-2 logits live in hlogit_kernel, NOT here (keeps registers lean —
// r11/r15 in-agg va-dots cost +5..11 us).
// ---------------------------------------------------------------------------
__global__ __launch_bounds__(256)
void agg_kernel(const int* __restrict__ row_ptr, const int* __restrict__ col_idx,
                const unsigned short* __restrict__ xWb,
                const float* __restrict__ as_, const float* __restrict__ ad_,
                const float* __restrict__ bias, float* __restrict__ outf,
                unsigned short* __restrict__ hb, int N, int mode) {
    const int wv   = (blockIdx.x * 256 + threadIdx.x) >> 6;
    const int lane = threadIdx.x & 63;
    if (wv >= N) return;
    const int i    = wv;
    const int half = lane >> 5;          // edge stream
    const int sl   = lane & 31;
    const int hh   = sl >> 4;            // head of this sublane's channels
    const int cb   = hh * 128 + (sl & 15) * 8;   // 8-channel block base
    const float adi = ad_[i * 2 + hh];

    float acc[8] = {};
    float dn = 0.f;

    const int beg = row_ptr[i];
    const int end = row_ptr[i + 1];

    int k = beg + half;
    int j = (k < end) ? col_idx[k] : 0;
    for (; k < end; k += 2) {
        const int jn = (k + 2 < end) ? col_idx[k + 2] : 0;   // idx prefetch only
        float e = as_[j * 2 + hh] + adi;
        e = e > 0.f ? e : NEG * e;
        const float w = expf(e);
        const uint4 q = *reinterpret_cast<const uint4*>(&xWb[(size_t)j * HC + cb]);
        const unsigned qq[4] = {q.x, q.y, q.z, q.w};
        #pragma unroll
        for (int r = 0; r < 4; ++r) {
            const float flo = __uint_as_float(qq[r] << 16);
            const float fhi = __uint_as_float(qq[r] & 0xffff0000u);
            acc[r * 2 + 0] = fmaf(w, flo, acc[r * 2 + 0]);
            acc[r * 2 + 1] = fmaf(w, fhi, acc[r * 2 + 1]);
        }
        dn += w;
        j = jn;
    }

    // merge the two edge streams
    #pragma unroll
    for (int r = 0; r < 8; ++r) acc[r] += __shfl_xor(acc[r], 32);
    dn += __shfl_xor(dn, 32);

    if (lane < 32) {
        // self loop (bf16 row)
        float e = as_[i * 2 + hh] + adi;
        e = e > 0.f ? e : NEG * e;
        const float ws = expf(e);
        const uint4 q = *reinterpret_cast<const uint4*>(&xWb[(size_t)i * HC + cb]);
        const unsigned qq[4] = {q.x, q.y, q.z, q.w};
        #pragma unroll
        for (int r = 0; r < 4; ++r) {
            const float flo = __uint_as_float(qq[r] << 16);
            const float fhi = __uint_as_float(qq[r] & 0xffff0000u);
            acc[r * 2 + 0] = fmaf(ws, flo, acc[r * 2 + 0]);
            acc[r * 2 + 1] = fmaf(ws, fhi, acc[r * 2 + 1]);
        }
        dn += ws;

        const float inv = 1.f / dn;
        const float4 b0 = *reinterpret_cast<const float4*>(&bias[cb]);
        const float4 b1 = *reinterpret_cast<const float4*>(&bias[cb + 4]);
        float o[8];
        o[0] = acc[0] * inv + b0.x; o[1] = acc[1] * inv + b0.y;
        o[2] = acc[2] * inv + b0.z; o[3] = acc[3] * inv + b0.w;
        o[4] = acc[4] * inv + b1.x; o[5] = acc[5] * inv + b1.y;
        o[6] = acc[6] * inv + b1.z; o[7] = acc[7] * inv + b1.w;

        if (mode) {
            // ELU then single bf16 row write (leaner than r8's dual-plane)
            #pragma unroll
            for (int r = 0; r < 8; ++r) o[r] = o[r] > 0.f ? o[r] : expm1f(o[r]);
            bfrag8 hv;
            #pragma unroll
            for (int r = 0; r < 8; ++r) hv[r] = (short)f2bf_rne(o[r]);
            *reinterpret_cast<bfrag8*>(&hb[(size_t)i * HC + cb]) = hv;
        } else {
            *reinterpret_cast<float4*>(&outf[(size_t)i * HC + cb]) =
                make_float4(o[0], o[1], o[2], o[3]);
            *reinterpret_cast<float4*>(&outf[(size_t)i * HC + cb + 4]) =
                make_float4(o[4], o[5], o[6], o[7]);
        }
    }
}

// ---------------------------------------------------------------------------
extern "C" void kernel_launch(void* const* d_in, const int* in_sizes, int n_in,
                              void* d_out, int out_size, void* d_ws, size_t ws_size,
                              hipStream_t stream) {
    const float* x      = (const float*)d_in[0];
    const int*   ei     = (const int*)d_in[1];
    const float* W1     = (const float*)d_in[2];
    const float* a_src1 = (const float*)d_in[3];
    const float* a_dst1 = (const float*)d_in[4];
    const float* b1     = (const float*)d_in[5];
    const float* W2     = (const float*)d_in[6];
    const float* a_src2 = (const float*)d_in[7];
    const float* a_dst2 = (const float*)d_in[8];
    const float* b2     = (const float*)d_in[9];
    float* out = (float*)d_out;

    const int Nn = in_sizes[0] / 128;   // 50000 nodes
    const int E  = in_sizes[1] / 2;     // 800000 edges
    const int K1 = in_sizes[2] / HC;    // 128
    const int* src = ei;
    const int* dst = ei + E;

    // workspace layout (fp32, int, then 32B-aligned bf16 region)
    float* as1   = (float*)d_ws;                  // Nn*2
    float* ad1   = as1 + (size_t)Nn * 2;
    float* as2   = ad1 + (size_t)Nn * 2;
    float* ad2   = as2 + (size_t)Nn * 2;
    float* va1   = ad2 + (size_t)Nn * 2;          // K1*4
    float* va2   = va1 + (size_t)K1 * 4;          // HC*4
    int*   tmp   = (int*)(va2 + (size_t)HC * 4);  // Nn
    int*   chunk = tmp + Nn;                      // 256
    int*   rowp  = chunk + 256;                   // Nn+1
    int*   curs  = rowp + (Nn + 1);               // Nn
    int*   colx  = curs + Nn;                     // E
    uintptr_t pa = ((uintptr_t)(colx + E) + 31) & ~(uintptr_t)31;
    unsigned short* wt1 = (unsigned short*)pa;           // HC*K1
    unsigned short* wt2 = wt1 + (size_t)HC * K1;         // HC*HC
    unsigned short* xb  = wt2 + (size_t)HC * HC;         // Nn*K1
    unsigned short* xWb = xb  + (size_t)Nn * K1;         // Nn*HC (messages)
    unsigned short* hb  = xWb + (size_t)Nn * HC;         // Nn*HC (h bf16)

    const int nb  = (Nn + 255) / 256;
    const int nxp = (Nn + 3) / 4;
    const int nhb = (E + 255) / 256;

    // ---- prep (fused) + CSR build ----
    hipMemsetAsync(tmp, 0, (size_t)Nn * sizeof(int), stream);
    prep_w_kernel<<<(K1 * HC + HC * HC + 255) / 256, 256, 0, stream>>>(W1, W2, wt1, wt2, K1);
    prep_va_kernel<<<(K1 + HC + 3) / 4, 256, 0, stream>>>(W1, a_src1, a_dst1, va1,
                                                          W2, a_src2, a_dst2, va2, K1);
    xprep_hist_kernel<<<nxp + nhb, 256, 0, stream>>>(x, va1, xb, as1, ad1, Nn, K1,
                                                     dst, tmp, E, nxp);
    scan_local_kernel<<<nb, 256, 0, stream>>>(tmp, chunk, Nn);
    scan_chunks_kernel<<<1, 256, 0, stream>>>(chunk, nb);
    add_offsets_kernel<<<nb, 256, 0, stream>>>(tmp, chunk, rowp, curs, Nn, E);
    scatter_kernel<<<nhb, 256, 0, stream>>>(src, dst, curs, colx, E);

    const dim3 ggrid((Nn + 127) / 128, HC / 128);
    const int  agrid = (Nn + 3) / 4;   // one wave per node

    // ---- layer 1 ----
    gemm_msg_kernel<<<ggrid, 256, 0, stream>>>(xb, wt1, xWb, Nn, K1);
    agg_kernel<<<agrid, 256, 0, stream>>>(rowp, colx, xWb, as1, ad1, b1,
                                          (float*)nullptr, hb, Nn, 1);
    hlogit_kernel<<<agrid, 256, 0, stream>>>(hb, va2, as2, ad2, Nn);

    // ---- layer 2 ----
    gemm_msg_kernel<<<ggrid, 256, 0, stream>>>(hb, wt2, xWb, Nn, HC);
    agg_kernel<<<agrid, 256, 0, stream>>>(rowp, colx, xWb, as2, ad2, b2,
                                          out, (unsigned short*)nullptr, Nn, 0);
}

// Round 17
// 325.431 us; speedup vs baseline: 1.0437x; 1.0437x over previous
//
#include <hip/hip_runtime.h>
#include <math.h>

#define HEADS 2
#define CH    128          // per-head channels
#define HC    256          // HEADS*CH
#define NEG   0.2f         // leaky_relu slope

typedef __attribute__((ext_vector_type(8))) short  bfrag8;   // 8 bf16 (4 VGPR)
typedef __attribute__((ext_vector_type(4))) float  f32x4;    // MFMA accumulator

// round-to-nearest-even fp32 -> bf16 (as raw u16)
__device__ inline unsigned short f2bf_rne(float x) {
    unsigned u = __float_as_uint(x);
    u += 0x7fffu + ((u >> 16) & 1u);
    return (unsigned short)(u >> 16);
}

// ---------------------------------------------------------------------------
// fused va for both layers: va[k][4] = {src_h0, src_h1, dst_h0, dst_h1}
// one wave per k row. (separate dispatch: xprep in prep_big reads va1)
// ---------------------------------------------------------------------------
__device__ inline void va_row(const float* __restrict__ W, const float* __restrict__ a_src,
                              const float* __restrict__ a_dst, float* __restrict__ va,
                              int k, int lane) {
    const int c0 = lane * 4;
    const float4 w4 = *reinterpret_cast<const float4*>(&W[(size_t)k * HC + c0]);
    const float4 s4 = *reinterpret_cast<const float4*>(&a_src[c0]);
    const float4 d4 = *reinterpret_cast<const float4*>(&a_dst[c0]);
    float ps = w4.x * s4.x + w4.y * s4.y + w4.z * s4.z + w4.w * s4.w;
    float pd = w4.x * d4.x + w4.y * d4.y + w4.z * d4.z + w4.w * d4.w;
    #pragma unroll
    for (int m = 1; m <= 16; m <<= 1) {
        ps += __shfl_xor(ps, m);
        pd += __shfl_xor(pd, m);
    }
    if (lane == 0)  { va[k * 4 + 0] = ps; va[k * 4 + 2] = pd; }
    if (lane == 32) { va[k * 4 + 1] = ps; va[k * 4 + 3] = pd; }
}

__global__ __launch_bounds__(256)
void prep_va_kernel(const float* __restrict__ W1, const float* __restrict__ as1,
                    const float* __restrict__ ad1, float* __restrict__ va1,
                    const float* __restrict__ W2, const float* __restrict__ as2,
                    const float* __restrict__ ad2, float* __restrict__ va2, int K1) {
    int g = (blockIdx.x * 256 + threadIdx.x) >> 6;
    const int lane = threadIdx.x & 63;
    if (g < K1)           va_row(W1, as1, ad1, va1, g, lane);
    else { g -= K1; if (g < HC) va_row(W2, as2, ad2, va2, g, lane); }
}

// ---------------------------------------------------------------------------
// prep_big: one dispatch, partitioned grid.
//   blocks [0, nW)            : W1/W2 cast+transpose to bf16
//   blocks [nW, nW+nxp)       : xprep (bf16 cast of x + exact fp32 logits)
//   blocks [nW+nxp, ...+nhb)  : hist (dst histogram, atomics)
// ---------------------------------------------------------------------------
__global__ __launch_bounds__(256)
void prep_big_kernel(const float* __restrict__ W1, const float* __restrict__ W2,
                     unsigned short* __restrict__ wt1, unsigned short* __restrict__ wt2,
                     const float* __restrict__ x, const float* __restrict__ va,
                     unsigned short* __restrict__ xb, float* __restrict__ as_out,
                     float* __restrict__ ad_out,
                     const int* __restrict__ dst, int* __restrict__ counts,
                     int N, int K1, int E, int nW, int nxp) {
    const int bx = (int)blockIdx.x;
    if (bx < nW) {
        int idx = bx * 256 + threadIdx.x;
        const int n1 = K1 * HC;
        if (idx < n1) {
            const int k = idx >> 8, n = idx & 255;
            wt1[(size_t)n * K1 + k] = f2bf_rne(W1[idx]);
        } else {
            idx -= n1;
            if (idx < HC * HC) {
                const int k = idx >> 8, n = idx & 255;
                wt2[(size_t)n * HC + k] = f2bf_rne(W2[idx]);
            }
        }
        return;
    }
    if (bx < nW + nxp) {
        const int i    = ((bx - nW) * 256 + threadIdx.x) >> 6;
        const int lane = threadIdx.x & 63;
        if (i >= N) return;
        const float2 v = reinterpret_cast<const float2*>(&x[(size_t)i * K1])[lane];
        ushort2 bv; bv.x = f2bf_rne(v.x); bv.y = f2bf_rne(v.y);
        reinterpret_cast<ushort2*>(&xb[(size_t)i * K1])[lane] = bv;

        const float4 a0 = reinterpret_cast<const float4*>(va)[lane * 2 + 0];
        const float4 a1 = reinterpret_cast<const float4*>(va)[lane * 2 + 1];
        float p0 = v.x * a0.x + v.y * a1.x;
        float p1 = v.x * a0.y + v.y * a1.y;
        float p2 = v.x * a0.z + v.y * a1.z;
        float p3 = v.x * a0.w + v.y * a1.w;
        #pragma unroll
        for (int m = 1; m <= 32; m <<= 1) {
            p0 += __shfl_xor(p0, m);
            p1 += __shfl_xor(p1, m);
            p2 += __shfl_xor(p2, m);
            p3 += __shfl_xor(p3, m);
        }
        if (lane == 0) {
            as_out[i * 2 + 0] = p0; as_out[i * 2 + 1] = p1;
            ad_out[i * 2 + 0] = p2; ad_out[i * 2 + 1] = p3;
        }
        return;
    }
    const int e = (bx - nW - nxp) * 256 + threadIdx.x;
    if (e < E) atomicAdd(&counts[dst[e]], 1);
}

// ---------------------------------------------------------------------------
// per-256-chunk exclusive scan, in place; chunk totals out
// ---------------------------------------------------------------------------
__global__ __launch_bounds__(256)
void scan_local_kernel(int* __restrict__ data, int* __restrict__ chunk_sum, int N) {
    __shared__ int s[256];
    const int t   = threadIdx.x;
    const int idx = blockIdx.x * 256 + t;
    const int v   = (idx < N) ? data[idx] : 0;
    s[t] = v;
    __syncthreads();
    #pragma unroll
    for (int off = 1; off < 256; off <<= 1) {
        int x = (t >= off) ? s[t - off] : 0;
        __syncthreads();
        s[t] += x;
        __syncthreads();
    }
    if (idx < N) data[idx] = s[t] - v;        // exclusive
    if (t == 255) chunk_sum[blockIdx.x] = s[255];
}

// ---------------------------------------------------------------------------
// offsets (fused chunk-scan): block bid reduces chunk_sum[0..bid) itself,
// then writes row_ptr/cursor. Valid for nb <= 256.
// ---------------------------------------------------------------------------
__global__ __launch_bounds__(256)
void offsets_kernel(const int* __restrict__ excl, const int* __restrict__ chunk_sum,
                    int* __restrict__ row_ptr, int* __restrict__ cursor,
                    int N, int E, int nb) {
    __shared__ int s[256];
    const int t   = threadIdx.x;
    const int bid = blockIdx.x;
    s[t] = (t < bid && t < nb) ? chunk_sum[t] : 0;
    __syncthreads();
    #pragma unroll
    for (int off = 128; off >= 1; off >>= 1) {
        if (t < off) s[t] += s[t + off];
        __syncthreads();
    }
    const int base = s[0];
    const int idx  = bid * 256 + t;
    if (idx < N) {
        const int rp = excl[idx] + base;
        row_ptr[idx] = rp;
        cursor[idx]  = rp;
    }
    if (idx == 0) row_ptr[N] = E;
}

// ---------------------------------------------------------------------------
// GEMM tile body (bf16 single-pass, 128x128, BK=64) — shared by both fused
// dispatch kernels below.
// ---------------------------------------------------------------------------
__device__ inline void gemm_tile(const unsigned short* __restrict__ Ab,
                                 const unsigned short* __restrict__ Wt,
                                 unsigned short* __restrict__ xWb, int M, int K,
                                 int bm, int bn,
                                 unsigned short (*Ah)[72], unsigned short (*Bh)[72]) {
    const int t    = threadIdx.x;
    const int row0 = bm * 128;
    const int col0 = bn * 128;
    const int lane = t & 63;
    const int wid  = t >> 6;
    const int wr   = wid >> 1;
    const int wc   = wid & 1;

    f32x4 acc[4][4] = {};

    const int arow = t & 127;
    const int aseg = (t >> 7) * 32;

    for (int kk = 0; kk < K; kk += 64) {
        {
            const int gr = row0 + arow;
            #pragma unroll
            for (int q = 0; q < 4; ++q) {
                bfrag8 v = {0,0,0,0,0,0,0,0};
                if (gr < M)
                    v = *reinterpret_cast<const bfrag8*>(&Ab[(size_t)gr * K + kk + aseg + q * 8]);
                *reinterpret_cast<bfrag8*>(&Ah[arow][aseg + q * 8]) = v;
            }
            #pragma unroll
            for (int q = 0; q < 4; ++q) {
                const bfrag8 w = *reinterpret_cast<const bfrag8*>(
                    &Wt[(size_t)(col0 + arow) * K + kk + aseg + q * 8]);
                *reinterpret_cast<bfrag8*>(&Bh[arow][aseg + q * 8]) = w;
            }
        }
        __syncthreads();

        const int ko = (lane >> 4) * 8;
        #pragma unroll
        for (int kb = 0; kb < 64; kb += 32) {
            bfrag8 ah[4], bh[4];
            #pragma unroll
            for (int m = 0; m < 4; ++m)
                ah[m] = *reinterpret_cast<const bfrag8*>(&Ah[wr * 64 + m * 16 + (lane & 15)][kb + ko]);
            #pragma unroll
            for (int n = 0; n < 4; ++n)
                bh[n] = *reinterpret_cast<const bfrag8*>(&Bh[wc * 64 + n * 16 + (lane & 15)][kb + ko]);
            #pragma unroll
            for (int m = 0; m < 4; ++m)
                #pragma unroll
                for (int n = 0; n < 4; ++n)
                    acc[m][n] = __builtin_amdgcn_mfma_f32_16x16x32_bf16(ah[m], bh[n], acc[m][n], 0, 0, 0);
        }
        __syncthreads();
    }

    #pragma unroll
    for (int m = 0; m < 4; ++m) {
        #pragma unroll
        for (int reg = 0; reg < 4; ++reg) {
            const int gr = row0 + wr * 64 + m * 16 + (lane >> 4) * 4 + reg;
            if (gr < M) {
                unsigned short* rp = &xWb[(size_t)gr * HC + col0];
                #pragma unroll
                for (int n = 0; n < 4; ++n)
                    rp[wc * 64 + n * 16 + (lane & 15)] = f2bf_rne(acc[m][n][reg]);
            }
        }
    }
}

// ---------------------------------------------------------------------------
// dispatch A: blocks [0, ngemm) = GEMM1 tiles; rest = CSR scatter.
// (both depend only on offsets; scatter's atomic traffic hides under MFMA)
// ---------------------------------------------------------------------------
__global__ __launch_bounds__(256)
void gemm1_scatter_kernel(const unsigned short* __restrict__ Ab,
                          const unsigned short* __restrict__ Wt,
                          unsigned short* __restrict__ xWb, int M, int K,
                          const int* __restrict__ src, const int* __restrict__ dst,
                          int* __restrict__ cursor, int* __restrict__ col_idx,
                          int E, int ngemm, int mtiles) {
    __shared__ unsigned short Ah[128][72];
    __shared__ unsigned short Bh[128][72];
    const int bx = (int)blockIdx.x;
    if (bx >= ngemm) {
        const int e = (bx - ngemm) * 256 + threadIdx.x;
        if (e < E) {
            const int pos = atomicAdd(&cursor[dst[e]], 1);
            col_idx[pos] = src[e];
        }
        return;
    }
    gemm_tile(Ab, Wt, xWb, M, K, bx % mtiles, bx / mtiles, Ah, Bh);
}

// ---------------------------------------------------------------------------
// dispatch B: blocks [0, ngemm) = GEMM2 tiles; rest = hlogit (layer-2 logits
// from bf16 h rows; logit error from bf16 h ~2e-3, negligible).
// ---------------------------------------------------------------------------
__global__ __launch_bounds__(256)
void gemm2_hlogit_kernel(const unsigned short* __restrict__ hb,
                         const unsigned short* __restrict__ Wt,
                         unsigned short* __restrict__ xWb, int M, int K,
                         const float* __restrict__ va,
                         float* __restrict__ as2, float* __restrict__ ad2,
                         int N, int ngemm, int mtiles) {
    __shared__ unsigned short Ah[128][72];
    __shared__ unsigned short Bh[128][72];
    const int bx = (int)blockIdx.x;
    if (bx >= ngemm) {
        const int i    = ((bx - ngemm) * 256 + threadIdx.x) >> 6;
        const int lane = threadIdx.x & 63;
        if (i >= N) return;
        const uint2 q = reinterpret_cast<const uint2*>(&hb[(size_t)i * HC])[lane];
        float f[4];
        f[0] = __uint_as_float(q.x << 16);
        f[1] = __uint_as_float(q.x & 0xffff0000u);
        f[2] = __uint_as_float(q.y << 16);
        f[3] = __uint_as_float(q.y & 0xffff0000u);
        float p0 = 0.f, p1 = 0.f, p2 = 0.f, p3 = 0.f;
        #pragma unroll
        for (int r = 0; r < 4; ++r) {
            const float4 vv = reinterpret_cast<const float4*>(va)[lane * 4 + r];
            p0 = fmaf(f[r], vv.x, p0);
            p1 = fmaf(f[r], vv.y, p1);
            p2 = fmaf(f[r], vv.z, p2);
            p3 = fmaf(f[r], vv.w, p3);
        }
        #pragma unroll
        for (int m = 1; m <= 32; m <<= 1) {
            p0 += __shfl_xor(p0, m);
            p1 += __shfl_xor(p1, m);
            p2 += __shfl_xor(p2, m);
            p3 += __shfl_xor(p3, m);
        }
        if (lane == 0) {
            as2[i * 2 + 0] = p0; as2[i * 2 + 1] = p1;
            ad2[i * 2 + 0] = p2; ad2[i * 2 + 1] = p3;
        }
        return;
    }
    gemm_tile(hb, Wt, xWb, M, K, bx % mtiles, bx / mtiles, Ah, Bh);
}

// ---------------------------------------------------------------------------
// gather aggregation: one wave per target node — EXACT r16 form (proven
// 79.5 us: bf16 messages, uint4+shift unpack, expf, 2 edge streams,
// idx-only prefetch, VGPR 20). mode 1: ELU -> bf16 h row. mode 0: fp32 out.
// ---------------------------------------------------------------------------
__global__ __launch_bounds__(256)
void agg_kernel(const int* __restrict__ row_ptr, const int* __restrict__ col_idx,
                const unsigned short* __restrict__ xWb,
                const float* __restrict__ as_, const float* __restrict__ ad_,
                const float* __restrict__ bias, float* __restrict__ outf,
                unsigned short* __restrict__ hb, int N, int mode) {
    const int wv   = (blockIdx.x * 256 + threadIdx.x) >> 6;
    const int lane = threadIdx.x & 63;
    if (wv >= N) return;
    const int i    = wv;
    const int half = lane >> 5;          // edge stream
    const int sl   = lane & 31;
    const int hh   = sl >> 4;            // head of this sublane's channels
    const int cb   = hh * 128 + (sl & 15) * 8;   // 8-channel block base
    const float adi = ad_[i * 2 + hh];

    float acc[8] = {};
    float dn = 0.f;

    const int beg = row_ptr[i];
    const int end = row_ptr[i + 1];

    int k = beg + half;
    int j = (k < end) ? col_idx[k] : 0;
    for (; k < end; k += 2) {
        const int jn = (k + 2 < end) ? col_idx[k + 2] : 0;   // idx prefetch only
        float e = as_[j * 2 + hh] + adi;
        e = e > 0.f ? e : NEG * e;
        const float w = expf(e);
        const uint4 q = *reinterpret_cast<const uint4*>(&xWb[(size_t)j * HC + cb]);
        const unsigned qq[4] = {q.x, q.y, q.z, q.w};
        #pragma unroll
        for (int r = 0; r < 4; ++r) {
            const float flo = __uint_as_float(qq[r] << 16);
            const float fhi = __uint_as_float(qq[r] & 0xffff0000u);
            acc[r * 2 + 0] = fmaf(w, flo, acc[r * 2 + 0]);
            acc[r * 2 + 1] = fmaf(w, fhi, acc[r * 2 + 1]);
        }
        dn += w;
        j = jn;
    }

    // merge the two edge streams
    #pragma unroll
    for (int r = 0; r < 8; ++r) acc[r] += __shfl_xor(acc[r], 32);
    dn += __shfl_xor(dn, 32);

    if (lane < 32) {
        // self loop (bf16 row)
        float e = as_[i * 2 + hh] + adi;
        e = e > 0.f ? e : NEG * e;
        const float ws = expf(e);
        const uint4 q = *reinterpret_cast<const uint4*>(&xWb[(size_t)i * HC + cb]);
        const unsigned qq[4] = {q.x, q.y, q.z, q.w};
        #pragma unroll
        for (int r = 0; r < 4; ++r) {
            const float flo = __uint_as_float(qq[r] << 16);
            const float fhi = __uint_as_float(qq[r] & 0xffff0000u);
            acc[r * 2 + 0] = fmaf(ws, flo, acc[r * 2 + 0]);
            acc[r * 2 + 1] = fmaf(ws, fhi, acc[r * 2 + 1]);
        }
        dn += ws;

        const float inv = 1.f / dn;
        const float4 b0 = *reinterpret_cast<const float4*>(&bias[cb]);
        const float4 b1 = *reinterpret_cast<const float4*>(&bias[cb + 4]);
        float o[8];
        o[0] = acc[0] * inv + b0.x; o[1] = acc[1] * inv + b0.y;
        o[2] = acc[2] * inv + b0.z; o[3] = acc[3] * inv + b0.w;
        o[4] = acc[4] * inv + b1.x; o[5] = acc[5] * inv + b1.y;
        o[6] = acc[6] * inv + b1.z; o[7] = acc[7] * inv + b1.w;

        if (mode) {
            #pragma unroll
            for (int r = 0; r < 8; ++r) o[r] = o[r] > 0.f ? o[r] : expm1f(o[r]);
            bfrag8 hv;
            #pragma unroll
            for (int r = 0; r < 8; ++r) hv[r] = (short)f2bf_rne(o[r]);
            *reinterpret_cast<bfrag8*>(&hb[(size_t)i * HC + cb]) = hv;
        } else {
            *reinterpret_cast<float4*>(&outf[(size_t)i * HC + cb]) =
                make_float4(o[0], o[1], o[2], o[3]);
            *reinterpret_cast<float4*>(&outf[(size_t)i * HC + cb + 4]) =
                make_float4(o[4], o[5], o[6], o[7]);
        }
    }
}

// ---------------------------------------------------------------------------
extern "C" void kernel_launch(void* const* d_in, const int* in_sizes, int n_in,
                              void* d_out, int out_size, void* d_ws, size_t ws_size,
                              hipStream_t stream) {
    const float* x      = (const float*)d_in[0];
    const int*   ei     = (const int*)d_in[1];
    const float* W1     = (const float*)d_in[2];
    const float* a_src1 = (const float*)d_in[3];
    const float* a_dst1 = (const float*)d_in[4];
    const float* b1     = (const float*)d_in[5];
    const float* W2     = (const float*)d_in[6];
    const float* a_src2 = (const float*)d_in[7];
    const float* a_dst2 = (const float*)d_in[8];
    const float* b2     = (const float*)d_in[9];
    float* out = (float*)d_out;

    const int Nn = in_sizes[0] / 128;   // 50000 nodes
    const int E  = in_sizes[1] / 2;     // 800000 edges
    const int K1 = in_sizes[2] / HC;    // 128
    const int* src = ei;
    const int* dst = ei + E;

    // workspace layout (fp32, int, then 32B-aligned bf16 region)
    float* as1   = (float*)d_ws;                  // Nn*2
    float* ad1   = as1 + (size_t)Nn * 2;
    float* as2   = ad1 + (size_t)Nn * 2;
    float* ad2   = as2 + (size_t)Nn * 2;
    float* va1   = ad2 + (size_t)Nn * 2;          // K1*4
    float* va2   = va1 + (size_t)K1 * 4;          // HC*4
    int*   tmp   = (int*)(va2 + (size_t)HC * 4);  // Nn
    int*   chunk = tmp + Nn;                      // 256
    int*   rowp  = chunk + 256;                   // Nn+1
    int*   curs  = rowp + (Nn + 1);               // Nn
    int*   colx  = curs + Nn;                     // E
    uintptr_t pa = ((uintptr_t)(colx + E) + 31) & ~(uintptr_t)31;
    unsigned short* wt1 = (unsigned short*)pa;           // HC*K1
    unsigned short* wt2 = wt1 + (size_t)HC * K1;         // HC*HC
    unsigned short* xb  = wt2 + (size_t)HC * HC;         // Nn*K1
    unsigned short* xWb = xb  + (size_t)Nn * K1;         // Nn*HC (messages)
    unsigned short* hb  = xWb + (size_t)Nn * HC;         // Nn*HC (h bf16)

    const int nb  = (Nn + 255) / 256;               // scan chunks (196)
    const int nxp = (Nn + 3) / 4;                   // xprep blocks (12500)
    const int nhb = (E + 255) / 256;                // hist/scatter blocks (3125)
    const int nW  = (K1 * HC + HC * HC + 255) / 256; // wcast blocks (384)
    const int mt1 = (Nn + 127) / 128;               // gemm m-tiles (391)
    const int ng  = mt1 * (HC / 128);               // gemm blocks (782)
    const int agrid = nxp;                          // one wave per node

    // ---- prep + CSR build (fused into 5 dispatches) ----
    hipMemsetAsync(tmp, 0, (size_t)Nn * sizeof(int), stream);
    prep_va_kernel<<<(K1 + HC + 3) / 4, 256, 0, stream>>>(W1, a_src1, a_dst1, va1,
                                                          W2, a_src2, a_dst2, va2, K1);
    prep_big_kernel<<<nW + nxp + nhb, 256, 0, stream>>>(W1, W2, wt1, wt2,
                                                        x, va1, xb, as1, ad1,
                                                        dst, tmp, Nn, K1, E, nW, nxp);
    scan_local_kernel<<<nb, 256, 0, stream>>>(tmp, chunk, Nn);
    offsets_kernel<<<nb, 256, 0, stream>>>(tmp, chunk, rowp, curs, Nn, E, nb);

    // ---- layer 1 (GEMM1 overlapped with CSR scatter) ----
    gemm1_scatter_kernel<<<ng + nhb, 256, 0, stream>>>(xb, wt1, xWb, Nn, K1,
                                                       src, dst, curs, colx, E, ng, mt1);
    agg_kernel<<<agrid, 256, 0, stream>>>(rowp, colx, xWb, as1, ad1, b1,
                                          (float*)nullptr, hb, Nn, 1);

    // ---- layer 2 (GEMM2 overlapped with hlogit) ----
    gemm2_hlogit_kernel<<<ng + agrid, 256, 0, stream>>>(hb, wt2, xWb, Nn, HC,
                                                        va2, as2, ad2, Nn, ng, mt1);
    agg_kernel<<<agrid, 256, 0, stream>>>(rowp, colx, xWb, as2, ad2, b2,
                                          out, (unsigned short*)nullptr, Nn, 0);
}